// Round 21
// baseline (457.972 us; speedup 1.0000x reference)
//
#include <hip/hip_runtime.h>

#define NN 50000
#define NE 800000
#define TE (NE + NN)
#define NRANGE 8
#define RSPAN ((NN + NRANGE - 1) / NRANGE)   // 6250

__device__ __forceinline__ float lrelu02(float x) { return x >= 0.f ? x : 0.2f * x; }

typedef const __attribute__((address_space(1))) unsigned int* gas_ptr;
typedef __attribute__((address_space(3))) unsigned int* las_ptr;
typedef _Float16 vh4 __attribute__((ext_vector_type(4)));
typedef unsigned int vu2 __attribute__((ext_vector_type(2)));
typedef float vf4 __attribute__((ext_vector_type(4)));
typedef float vf2 __attribute__((ext_vector_type(2)));

__device__ __forceinline__ void dma16(const float* g, float* l) {
    __builtin_amdgcn_global_load_lds((gas_ptr)g, (las_ptr)l, 16, 0, 0);
}

// Count: 8x blocks; block (chunk, r=blockIdx&7) handles only dst-range r ->
// counts lines for range r are touched by one XCD only (round-robin dispatch).
__global__ void k_count(const int* __restrict__ ei, int* __restrict__ counts) {
    int r = blockIdx.x & 7;
    int e = (blockIdx.x >> 3) * 256 + threadIdx.x;
    if (e >= TE) return;
    int dst = (e < NE) ? ei[NE + e] : (e - NE);
    if (dst >= r * RSPAN && dst < (r + 1) * RSPAN)
        atomicAdd(&counts[dst], 1);
}

__global__ void k_bsum(const int* __restrict__ counts, int* __restrict__ bsums) {
    __shared__ int sm[1024];
    int i = blockIdx.x * 1024 + threadIdx.x;
    sm[threadIdx.x] = (i < NN) ? counts[i] : 0;
    __syncthreads();
    for (int off = 512; off > 0; off >>= 1) {
        if ((int)threadIdx.x < off) sm[threadIdx.x] += sm[threadIdx.x + off];
        __syncthreads();
    }
    if (threadIdx.x == 0) bsums[blockIdx.x] = sm[0];
}

__global__ void k_bscan(const int* __restrict__ bsums, int* __restrict__ bex, int nb) {
    int l = threadIdx.x;
    int v = (l < nb) ? bsums[l] : 0;
    int orig = v;
    for (int d = 1; d < 64; d <<= 1) {
        int t = __shfl_up(v, d);
        if (l >= d) v += t;
    }
    if (l <= nb) bex[l] = v - orig;
}

__global__ void k_scan(const int* __restrict__ counts, const int* __restrict__ bex,
                       int* __restrict__ rowptr, int* __restrict__ cursor) {
    __shared__ int sm[1024];
    int t = threadIdx.x;
    int i = blockIdx.x * 1024 + t;
    int c = (i < NN) ? counts[i] : 0;
    sm[t] = c;
    __syncthreads();
    for (int off = 1; off < 1024; off <<= 1) {
        int v = (t >= off) ? sm[t - off] : 0;
        __syncthreads();
        sm[t] += v;
        __syncthreads();
    }
    int ex = bex[blockIdx.x] + sm[t] - c;
    if (i <= NN) rowptr[i] = ex;
    if (i < NN) cursor[i] = ex;
}

// Scatter: 8x dst-range split -> csr lines of range r written from one XCD.
__global__ void k_scatter(const int* __restrict__ ei, int* __restrict__ cursor, int* __restrict__ csr) {
    int r = blockIdx.x & 7;
    int e = (blockIdx.x >> 3) * 256 + threadIdx.x;
    if (e >= TE) return;
    int dst = (e < NE) ? ei[NE + e] : (e - NE);
    if (dst >= r * RSPAN && dst < (r + 1) * RSPAN) {
        int src = (e < NE) ? ei[e] : dst;
        int pos = atomicAdd(&cursor[dst], 1);
        csr[pos] = src;
    }
}

// GEMM X[N,128] @ W[128,128] -> XS[N,128] (FP16) + AL logits (fp32).
// Round-13 structure; XS stored fp16 NT.
__global__ __launch_bounds__(256) void k_gemm(const float* __restrict__ X, const float* __restrict__ W,
                                              const float* __restrict__ as_, const float* __restrict__ ad_,
                                              _Float16* __restrict__ XS, float* __restrict__ AL) {
    __shared__ float sX[64 * 128];   // 32 KB
    int t = threadIdx.x;
    int lane = t & 63;
    int wv = __builtin_amdgcn_readfirstlane(t >> 6);
    int tc = t & 31;
    int tr = t >> 5;
    size_t chunk = (size_t)blockIdx.x * 64;
    size_t base = chunk * 128;
    const size_t gmax = (size_t)NN * 128 - 4;
#pragma unroll
    for (int i = 0; i < 8; i++) {
        size_t off = ((size_t)(wv * 8 + i)) * 256 + (size_t)lane * 4;
        size_t g = base + off;
        if (g > gmax) g = gmax;
        dma16(X + g, &sX[off]);
    }
    __syncthreads();
    float4 av = *(const float4*)(as_ + tc * 4);
    float4 dv = *(const float4*)(ad_ + tc * 4);
    float acc[8][4];
#pragma unroll
    for (int i = 0; i < 8; i++)
#pragma unroll
        for (int j = 0; j < 4; j++) acc[i][j] = 0.f;
#pragma unroll 2
    for (int kk = 0; kk < 128; kk += 4) {
        float4 wq[4];
#pragma unroll
        for (int k = 0; k < 4; k++)
            wq[k] = *(const float4*)(W + (size_t)(kk + k) * 128 + tc * 4);
#pragma unroll
        for (int i = 0; i < 8; i++) {
            float4 xv = *(const float4*)(&sX[(tr * 8 + i) * 128 + kk]);
            acc[i][0] = fmaf(xv.x, wq[0].x, acc[i][0]);
            acc[i][1] = fmaf(xv.x, wq[0].y, acc[i][1]);
            acc[i][2] = fmaf(xv.x, wq[0].z, acc[i][2]);
            acc[i][3] = fmaf(xv.x, wq[0].w, acc[i][3]);
            acc[i][0] = fmaf(xv.y, wq[1].x, acc[i][0]);
            acc[i][1] = fmaf(xv.y, wq[1].y, acc[i][1]);
            acc[i][2] = fmaf(xv.y, wq[1].z, acc[i][2]);
            acc[i][3] = fmaf(xv.y, wq[1].w, acc[i][3]);
            acc[i][0] = fmaf(xv.z, wq[2].x, acc[i][0]);
            acc[i][1] = fmaf(xv.z, wq[2].y, acc[i][1]);
            acc[i][2] = fmaf(xv.z, wq[2].z, acc[i][2]);
            acc[i][3] = fmaf(xv.z, wq[2].w, acc[i][3]);
            acc[i][0] = fmaf(xv.w, wq[3].x, acc[i][0]);
            acc[i][1] = fmaf(xv.w, wq[3].y, acc[i][1]);
            acc[i][2] = fmaf(xv.w, wq[3].z, acc[i][2]);
            acc[i][3] = fmaf(xv.w, wq[3].w, acc[i][3]);
        }
    }
#pragma unroll
    for (int i = 0; i < 8; i++) {
        size_t row = chunk + tr * 8 + i;
        bool ok = row < NN;
        if (ok) {
            vh4 hv;
            hv.x = (_Float16)acc[i][0];
            hv.y = (_Float16)acc[i][1];
            hv.z = (_Float16)acc[i][2];
            hv.w = (_Float16)acc[i][3];
            vu2 u = __builtin_bit_cast(vu2, hv);
            __builtin_nontemporal_store(u, (vu2*)(XS + row * 128 + tc * 4));
        }
        float s = acc[i][0] * av.x + acc[i][1] * av.y + acc[i][2] * av.z + acc[i][3] * av.w;
        float dd = acc[i][0] * dv.x + acc[i][1] * dv.y + acc[i][2] * dv.z + acc[i][3] * dv.w;
#pragma unroll
        for (int off = 8; off > 0; off >>= 1) {
            s += __shfl_xor(s, off);
            dd += __shfl_xor(dd, off);
        }
        if (ok && (tc & 15) == 0) {
            int h = tc >> 4;
            AL[row * 4 + h] = s;
            AL[row * 4 + 2 + h] = dd;
        }
    }
}

// Aggregation: PAIRED-EDGE fp16 gather. Each vh4 (8 B/lane) load covers TWO
// edge rows (lanes 0-31 even edge, 32-63 odd) -> gather instructions halve at
// unchanged bytes/MLP (8 loads in flight = 16 edges). Lane l5=lane&31 owns
// channels 4*l5..4*l5+3 (head=l5>>4). fp32 accumulation (numerics unchanged).
template <int LAST>
__global__ __launch_bounds__(256) void k_agg(const _Float16* __restrict__ XS, const float* __restrict__ AL,
                                             const int* __restrict__ rowptr, const int* __restrict__ csr,
                                             const float* __restrict__ bias, const float* __restrict__ lp_w,
                                             const float* __restrict__ lp_b, const float* __restrict__ prelu_a,
                                             float* __restrict__ out) {
    int wv = threadIdx.x >> 6, lane = threadIdx.x & 63;
    int n = blockIdx.x * 4 + wv;
    if (n >= NN) return;
    int beg = rowptr[n], end = rowptr[n + 1];
    float2 aldv = *(const float2*)(AL + (size_t)n * 4 + 2);
    float ald0 = aldv.x, ald1 = aldv.y;
    int half = lane >> 5;    // which edge of the pair
    int l5 = lane & 31;      // channel quad index
    int hsel = l5 >> 4;      // head of this lane's channels
    float a0 = 0.f, a1 = 0.f, a2 = 0.f, a3 = 0.f;
    float den0 = 0.f, den1 = 0.f;
    for (int base = beg; base < end; base += 64) {
        int i = base + lane;
        float w0 = 0.f, w1 = 0.f;
        int sv = 0;
        if (i < end) {
            sv = csr[i];
            float2 av = *(const float2*)(AL + (size_t)sv * 4);
            w0 = __expf(lrelu02(av.x + ald0));
            w1 = __expf(lrelu02(av.y + ald1));
        }
        den0 += w0;
        den1 += w1;
        int cnt = min(64, end - base);
        int j = 0;
        for (; j + 16 <= cnt; j += 16) {
            int s[16];
#pragma unroll
            for (int jj = 0; jj < 16; jj++) s[jj] = __shfl(sv, j + jj);   // uniform -> readlane
            vh4 xv[8];
#pragma unroll
            for (int p = 0; p < 8; p++) {
                int row = half ? s[2 * p + 1] : s[2 * p];
                xv[p] = *(const vh4*)(XS + (size_t)row * 128 + 4 * l5);
            }
            float wA[16], wB[16];
#pragma unroll
            for (int jj = 0; jj < 16; jj++) {
                wA[jj] = __shfl(w0, j + jj);
                wB[jj] = __shfl(w1, j + jj);
            }
#pragma unroll
            for (int p = 0; p < 8; p++) {
                float we0 = hsel ? wB[2 * p] : wA[2 * p];
                float we1 = hsel ? wB[2 * p + 1] : wA[2 * p + 1];
                float w = half ? we1 : we0;
                a0 = fmaf(w, (float)xv[p].x, a0);
                a1 = fmaf(w, (float)xv[p].y, a1);
                a2 = fmaf(w, (float)xv[p].z, a2);
                a3 = fmaf(w, (float)xv[p].w, a3);
            }
        }
        for (; j < cnt; j++) {
            int s = __shfl(sv, j);
            float wa = __shfl(w0, j), wb = __shfl(w1, j);
            float w = hsel ? wb : wa;
            if (half == 0) {
                vh4 xv = *(const vh4*)(XS + (size_t)s * 128 + 4 * l5);
                a0 = fmaf(w, (float)xv.x, a0);
                a1 = fmaf(w, (float)xv.y, a1);
                a2 = fmaf(w, (float)xv.z, a2);
                a3 = fmaf(w, (float)xv.w, a3);
            }
        }
    }
    // fold odd-edge half into even-edge half
    a0 += __shfl_xor(a0, 32);
    a1 += __shfl_xor(a1, 32);
    a2 += __shfl_xor(a2, 32);
    a3 += __shfl_xor(a3, 32);
#pragma unroll
    for (int off = 32; off > 0; off >>= 1) {
        den0 += __shfl_xor(den0, off);
        den1 += __shfl_xor(den1, off);
    }
    float pa = prelu_a[0];
    float inv = 1.f / ((hsel ? den1 : den0) + 1e-16f);
    if (LAST) {
        float v0 = a0 * inv, v1 = a1 * inv, v2 = a2 * inv, v3 = a3 * inv;
        float o0 = __shfl_xor(v0, 16), o1 = __shfl_xor(v1, 16);
        float o2 = __shfl_xor(v2, 16), o3 = __shfl_xor(v3, 16);
        float p = 0.f;
        if (lane < 16) {   // half==0, head0 lanes pair with head1 via xor 16
            int c = 4 * l5;
            float m0 = 0.5f * (v0 + o0) + bias[c];
            float m1 = 0.5f * (v1 + o1) + bias[c + 1];
            float m2 = 0.5f * (v2 + o2) + bias[c + 2];
            float m3 = 0.5f * (v3 + o3) + bias[c + 3];
            m0 = m0 >= 0.f ? m0 : pa * m0;
            m1 = m1 >= 0.f ? m1 : pa * m1;
            m2 = m2 >= 0.f ? m2 : pa * m2;
            m3 = m3 >= 0.f ? m3 : pa * m3;
            p = m0 * lp_w[c] + m1 * lp_w[c + 1] + m2 * lp_w[c + 2] + m3 * lp_w[c + 3];
        }
        p += __shfl_xor(p, 1);
        p += __shfl_xor(p, 2);
        p += __shfl_xor(p, 4);
        p += __shfl_xor(p, 8);
        if (lane == 0) out[n] = p + lp_b[0];
    } else {
        if (half == 0) {
            int c = 4 * l5;
            float4 bv = *(const float4*)(bias + c);
            float m0 = a0 * inv + bv.x;
            float m1 = a1 * inv + bv.y;
            float m2 = a2 * inv + bv.z;
            float m3 = a3 * inv + bv.w;
            m0 = m0 >= 0.f ? m0 : pa * m0;
            m1 = m1 >= 0.f ? m1 : pa * m1;
            m2 = m2 >= 0.f ? m2 : pa * m2;
            m3 = m3 >= 0.f ? m3 : pa * m3;
            vf4 o; o.x = m0; o.y = m1; o.z = m2; o.w = m3;
            __builtin_nontemporal_store(o, (vf4*)(out + (size_t)n * 128 + c));
        }
    }
}

extern "C" void kernel_launch(void* const* d_in, const int* in_sizes, int n_in,
                              void* d_out, int out_size, void* d_ws, size_t ws_size,
                              hipStream_t stream) {
    const float* x   = (const float*)d_in[0];
    const int*   ei  = (const int*)d_in[1];
    const float* W1  = (const float*)d_in[2];
    const float* as1 = (const float*)d_in[3];
    const float* ad1 = (const float*)d_in[4];
    const float* b1  = (const float*)d_in[5];
    const float* W2  = (const float*)d_in[6];
    const float* as2 = (const float*)d_in[7];
    const float* ad2 = (const float*)d_in[8];
    const float* b2  = (const float*)d_in[9];
    const float* W3  = (const float*)d_in[10];
    const float* as3 = (const float*)d_in[11];
    const float* ad3 = (const float*)d_in[12];
    const float* b3  = (const float*)d_in[13];
    const float* lpw = (const float*)d_in[14];
    const float* lpb = (const float*)d_in[15];
    const float* pa  = (const float*)d_in[16];
    float* out = (float*)d_out;

    char* ws = (char*)d_ws;
    size_t off = 0;
    auto alloc = [&](size_t bytes) {
        void* p = ws + off;
        off = (off + bytes + 255) & ~(size_t)255;
        return p;
    };
    int*      rowptr = (int*)alloc((NN + 1) * sizeof(int));
    int*      cursor = (int*)alloc((NN + 1) * sizeof(int));
    int*      counts = (int*)alloc((size_t)NN * sizeof(int));
    int*      bsums  = (int*)alloc(64 * sizeof(int));
    int*      bex    = (int*)alloc(64 * sizeof(int));
    int*      csr    = (int*)alloc((size_t)TE * sizeof(int));
    float*    al     = (float*)alloc((size_t)NN * 4 * sizeof(float));
    _Float16* xs     = (_Float16*)alloc((size_t)NN * 128 * sizeof(_Float16));
    float*    h      = (float*)alloc((size_t)NN * 128 * sizeof(float));
    (void)ws_size; (void)n_in; (void)in_sizes; (void)out_size;

    const int NB = (NN + 1023) / 1024;       // 49
    const int GEMM_GRID = (NN + 63) / 64;    // 782
    const int AGG_GRID  = (NN + 3) / 4;      // 12500
    const int EDGE_GRID = 8 * ((TE + 255) / 256);   // 8x range-split

    (void)hipMemsetAsync(counts, 0, (size_t)NN * sizeof(int), stream);
    k_count<<<EDGE_GRID, 256, 0, stream>>>(ei, counts);
    k_bsum<<<NB, 1024, 0, stream>>>(counts, bsums);
    k_bscan<<<1, 64, 0, stream>>>(bsums, bex, NB);
    k_scan<<<NB, 1024, 0, stream>>>(counts, bex, rowptr, cursor);
    k_scatter<<<EDGE_GRID, 256, 0, stream>>>(ei, cursor, csr);

    k_gemm<<<GEMM_GRID, 256, 0, stream>>>(x, W1, as1, ad1, xs, al);
    k_agg<0><<<AGG_GRID, 256, 0, stream>>>(xs, al, rowptr, csr, b1, nullptr, nullptr, pa, h);
    k_gemm<<<GEMM_GRID, 256, 0, stream>>>(h, W2, as2, ad2, xs, al);
    k_agg<0><<<AGG_GRID, 256, 0, stream>>>(xs, al, rowptr, csr, b2, nullptr, nullptr, pa, h);
    k_gemm<<<GEMM_GRID, 256, 0, stream>>>(h, W3, as3, ad3, xs, al);
    k_agg<1><<<AGG_GRID, 256, 0, stream>>>(xs, al, rowptr, csr, b3, lpw, lpb, pa, out);
}

// Round 22
// 308.650 us; speedup vs baseline: 1.4838x; 1.4838x over previous
//
#include <hip/hip_runtime.h>

#define NN 50000
#define NE 800000
#define TE (NE + NN)
#define NRANGE 8
#define RSPAN ((NN + NRANGE - 1) / NRANGE)   // 6250

__device__ __forceinline__ float lrelu02(float x) { return x >= 0.f ? x : 0.2f * x; }

typedef const __attribute__((address_space(1))) unsigned int* gas_ptr;
typedef __attribute__((address_space(3))) unsigned int* las_ptr;
typedef _Float16 vh4 __attribute__((ext_vector_type(4)));
typedef _Float16 vh2 __attribute__((ext_vector_type(2)));
typedef unsigned int vu2 __attribute__((ext_vector_type(2)));
typedef float vf2 __attribute__((ext_vector_type(2)));

__device__ __forceinline__ void dma16(const float* g, float* l) {
    __builtin_amdgcn_global_load_lds((gas_ptr)g, (las_ptr)l, 16, 0, 0);
}

// Count: 8x blocks; block (chunk, r=blockIdx&7) handles only dst-range r ->
// counts lines for range r are touched by one XCD only (round-robin dispatch).
__global__ void k_count(const int* __restrict__ ei, int* __restrict__ counts) {
    int r = blockIdx.x & 7;
    int e = (blockIdx.x >> 3) * 256 + threadIdx.x;
    if (e >= TE) return;
    int dst = (e < NE) ? ei[NE + e] : (e - NE);
    if (dst >= r * RSPAN && dst < (r + 1) * RSPAN)
        atomicAdd(&counts[dst], 1);
}

__global__ void k_bsum(const int* __restrict__ counts, int* __restrict__ bsums) {
    __shared__ int sm[1024];
    int i = blockIdx.x * 1024 + threadIdx.x;
    sm[threadIdx.x] = (i < NN) ? counts[i] : 0;
    __syncthreads();
    for (int off = 512; off > 0; off >>= 1) {
        if ((int)threadIdx.x < off) sm[threadIdx.x] += sm[threadIdx.x + off];
        __syncthreads();
    }
    if (threadIdx.x == 0) bsums[blockIdx.x] = sm[0];
}

__global__ void k_bscan(const int* __restrict__ bsums, int* __restrict__ bex, int nb) {
    int l = threadIdx.x;
    int v = (l < nb) ? bsums[l] : 0;
    int orig = v;
    for (int d = 1; d < 64; d <<= 1) {
        int t = __shfl_up(v, d);
        if (l >= d) v += t;
    }
    if (l <= nb) bex[l] = v - orig;
}

__global__ void k_scan(const int* __restrict__ counts, const int* __restrict__ bex,
                       int* __restrict__ rowptr, int* __restrict__ cursor) {
    __shared__ int sm[1024];
    int t = threadIdx.x;
    int i = blockIdx.x * 1024 + t;
    int c = (i < NN) ? counts[i] : 0;
    sm[t] = c;
    __syncthreads();
    for (int off = 1; off < 1024; off <<= 1) {
        int v = (t >= off) ? sm[t - off] : 0;
        __syncthreads();
        sm[t] += v;
        __syncthreads();
    }
    int ex = bex[blockIdx.x] + sm[t] - c;
    if (i <= NN) rowptr[i] = ex;
    if (i < NN) cursor[i] = ex;
}

// Scatter: 8x dst-range split -> csr lines of range r written from one XCD.
__global__ void k_scatter(const int* __restrict__ ei, int* __restrict__ cursor, int* __restrict__ csr) {
    int r = blockIdx.x & 7;
    int e = (blockIdx.x >> 3) * 256 + threadIdx.x;
    if (e >= TE) return;
    int dst = (e < NE) ? ei[NE + e] : (e - NE);
    if (dst >= r * RSPAN && dst < (r + 1) * RSPAN) {
        int src = (e < NE) ? ei[e] : dst;
        int pos = atomicAdd(&cursor[dst], 1);
        csr[pos] = src;
    }
}

// GEMM X[N,128] @ W[128,128] -> XS[N,128] (FP16) + AL logits (fp32).
// Round-13 structure; XS stored fp16 NT (halves agg's compulsory fill).
__global__ __launch_bounds__(256) void k_gemm(const float* __restrict__ X, const float* __restrict__ W,
                                              const float* __restrict__ as_, const float* __restrict__ ad_,
                                              _Float16* __restrict__ XS, float* __restrict__ AL) {
    __shared__ float sX[64 * 128];   // 32 KB
    int t = threadIdx.x;
    int lane = t & 63;
    int wv = __builtin_amdgcn_readfirstlane(t >> 6);
    int tc = t & 31;
    int tr = t >> 5;
    size_t chunk = (size_t)blockIdx.x * 64;
    size_t base = chunk * 128;
    const size_t gmax = (size_t)NN * 128 - 4;
#pragma unroll
    for (int i = 0; i < 8; i++) {
        size_t off = ((size_t)(wv * 8 + i)) * 256 + (size_t)lane * 4;
        size_t g = base + off;
        if (g > gmax) g = gmax;
        dma16(X + g, &sX[off]);
    }
    __syncthreads();
    float4 av = *(const float4*)(as_ + tc * 4);
    float4 dv = *(const float4*)(ad_ + tc * 4);
    float acc[8][4];
#pragma unroll
    for (int i = 0; i < 8; i++)
#pragma unroll
        for (int j = 0; j < 4; j++) acc[i][j] = 0.f;
#pragma unroll 2
    for (int kk = 0; kk < 128; kk += 4) {
        float4 wq[4];
#pragma unroll
        for (int k = 0; k < 4; k++)
            wq[k] = *(const float4*)(W + (size_t)(kk + k) * 128 + tc * 4);
#pragma unroll
        for (int i = 0; i < 8; i++) {
            float4 xv = *(const float4*)(&sX[(tr * 8 + i) * 128 + kk]);
            acc[i][0] = fmaf(xv.x, wq[0].x, acc[i][0]);
            acc[i][1] = fmaf(xv.x, wq[0].y, acc[i][1]);
            acc[i][2] = fmaf(xv.x, wq[0].z, acc[i][2]);
            acc[i][3] = fmaf(xv.x, wq[0].w, acc[i][3]);
            acc[i][0] = fmaf(xv.y, wq[1].x, acc[i][0]);
            acc[i][1] = fmaf(xv.y, wq[1].y, acc[i][1]);
            acc[i][2] = fmaf(xv.y, wq[1].z, acc[i][2]);
            acc[i][3] = fmaf(xv.y, wq[1].w, acc[i][3]);
            acc[i][0] = fmaf(xv.z, wq[2].x, acc[i][0]);
            acc[i][1] = fmaf(xv.z, wq[2].y, acc[i][1]);
            acc[i][2] = fmaf(xv.z, wq[2].z, acc[i][2]);
            acc[i][3] = fmaf(xv.z, wq[2].w, acc[i][3]);
            acc[i][0] = fmaf(xv.w, wq[3].x, acc[i][0]);
            acc[i][1] = fmaf(xv.w, wq[3].y, acc[i][1]);
            acc[i][2] = fmaf(xv.w, wq[3].z, acc[i][2]);
            acc[i][3] = fmaf(xv.w, wq[3].w, acc[i][3]);
        }
    }
#pragma unroll
    for (int i = 0; i < 8; i++) {
        size_t row = chunk + tr * 8 + i;
        bool ok = row < NN;
        if (ok) {
            vh4 hv;
            hv.x = (_Float16)acc[i][0];
            hv.y = (_Float16)acc[i][1];
            hv.z = (_Float16)acc[i][2];
            hv.w = (_Float16)acc[i][3];
            vu2 u = __builtin_bit_cast(vu2, hv);
            __builtin_nontemporal_store(u, (vu2*)(XS + row * 128 + tc * 4));
        }
        float s = acc[i][0] * av.x + acc[i][1] * av.y + acc[i][2] * av.z + acc[i][3] * av.w;
        float dd = acc[i][0] * dv.x + acc[i][1] * dv.y + acc[i][2] * dv.z + acc[i][3] * dv.w;
#pragma unroll
        for (int off = 8; off > 0; off >>= 1) {
            s += __shfl_xor(s, off);
            dd += __shfl_xor(dd, off);
        }
        if (ok && (tc & 15) == 0) {
            int h = tc >> 4;
            AL[row * 4 + h] = s;
            AL[row * 4 + 2 + h] = dd;
        }
    }
}

// Aggregation: round-4/7 structure, FP16 gather operand (4 B/lane, 256 B/row).
// fp32 accumulation; NT h stores. (Round-20 exact — proven 48us.)
template <int LAST>
__global__ __launch_bounds__(256) void k_agg(const _Float16* __restrict__ XS, const float* __restrict__ AL,
                                             const int* __restrict__ rowptr, const int* __restrict__ csr,
                                             const float* __restrict__ bias, const float* __restrict__ lp_w,
                                             const float* __restrict__ lp_b, const float* __restrict__ prelu_a,
                                             float* __restrict__ out) {
    int wv = threadIdx.x >> 6, lane = threadIdx.x & 63;
    int n = blockIdx.x * 4 + wv;
    if (n >= NN) return;
    int beg = rowptr[n], end = rowptr[n + 1];
    float2 aldv = *(const float2*)(AL + (size_t)n * 4 + 2);
    float ald0 = aldv.x, ald1 = aldv.y;
    float acc_lo = 0.f, acc_hi = 0.f, den0 = 0.f, den1 = 0.f;
    for (int base = beg; base < end; base += 64) {
        int i = base + lane;
        float w0 = 0.f, w1 = 0.f;
        int sv = 0;
        if (i < end) {
            sv = csr[i];
            float2 av = *(const float2*)(AL + (size_t)sv * 4);
            w0 = __expf(lrelu02(av.x + ald0));
            w1 = __expf(lrelu02(av.y + ald1));
        }
        den0 += w0;
        den1 += w1;
        int cnt = min(64, end - base);
        int j = 0;
        for (; j + 8 <= cnt; j += 8) {
            int s[8];
            float ww[8];
#pragma unroll
            for (int jj = 0; jj < 8; jj++) {
                s[jj] = __shfl(sv, j + jj);
                float q0 = __shfl(w0, j + jj), q1 = __shfl(w1, j + jj);
                ww[jj] = (lane < 32) ? q0 : q1;
            }
            vh2 xv[8];
#pragma unroll
            for (int jj = 0; jj < 8; jj++)
                xv[jj] = *(const vh2*)(XS + (size_t)s[jj] * 128 + 2 * lane);
#pragma unroll
            for (int jj = 0; jj < 8; jj++) {
                acc_lo = fmaf(ww[jj], (float)xv[jj].x, acc_lo);
                acc_hi = fmaf(ww[jj], (float)xv[jj].y, acc_hi);
            }
        }
        for (; j < cnt; j++) {
            int s = __shfl(sv, j);
            float q0 = __shfl(w0, j), q1 = __shfl(w1, j);
            float w = (lane < 32) ? q0 : q1;
            vh2 xv = *(const vh2*)(XS + (size_t)s * 128 + 2 * lane);
            acc_lo = fmaf(w, (float)xv.x, acc_lo);
            acc_hi = fmaf(w, (float)xv.y, acc_hi);
        }
    }
#pragma unroll
    for (int off = 32; off > 0; off >>= 1) {
        den0 += __shfl_xor(den0, off);
        den1 += __shfl_xor(den1, off);
    }
    float pa = prelu_a[0];
    float densel = (lane < 32) ? den0 : den1;
    float inv = 1.f / (densel + 1e-16f);
    if (LAST) {
        float hlo = acc_lo * inv, hhi = acc_hi * inv;
        float olo = __shfl_xor(hlo, 32), ohi = __shfl_xor(hhi, 32);
        float p = 0.f;
        if (lane < 32) {
            int c = 2 * lane;
            float v0 = 0.5f * (hlo + olo) + bias[c];
            float v1 = 0.5f * (hhi + ohi) + bias[c + 1];
            v0 = v0 >= 0.f ? v0 : pa * v0;
            v1 = v1 >= 0.f ? v1 : pa * v1;
            p = v0 * lp_w[c] + v1 * lp_w[c + 1];
        }
#pragma unroll
        for (int off = 32; off > 0; off >>= 1) p += __shfl_xor(p, off);
        if (lane == 0) out[n] = p + lp_b[0];
    } else {
        int c = 2 * lane;
        float2 bv = *(const float2*)(bias + c);
        float v0 = acc_lo * inv + bv.x;
        float v1 = acc_hi * inv + bv.y;
        v0 = v0 >= 0.f ? v0 : pa * v0;
        v1 = v1 >= 0.f ? v1 : pa * v1;
        vf2 o; o.x = v0; o.y = v1;
        __builtin_nontemporal_store(o, (vf2*)(out + (size_t)n * 128 + c));
    }
}

extern "C" void kernel_launch(void* const* d_in, const int* in_sizes, int n_in,
                              void* d_out, int out_size, void* d_ws, size_t ws_size,
                              hipStream_t stream) {
    const float* x   = (const float*)d_in[0];
    const int*   ei  = (const int*)d_in[1];
    const float* W1  = (const float*)d_in[2];
    const float* as1 = (const float*)d_in[3];
    const float* ad1 = (const float*)d_in[4];
    const float* b1  = (const float*)d_in[5];
    const float* W2  = (const float*)d_in[6];
    const float* as2 = (const float*)d_in[7];
    const float* ad2 = (const float*)d_in[8];
    const float* b2  = (const float*)d_in[9];
    const float* W3  = (const float*)d_in[10];
    const float* as3 = (const float*)d_in[11];
    const float* ad3 = (const float*)d_in[12];
    const float* b3  = (const float*)d_in[13];
    const float* lpw = (const float*)d_in[14];
    const float* lpb = (const float*)d_in[15];
    const float* pa  = (const float*)d_in[16];
    float* out = (float*)d_out;

    char* ws = (char*)d_ws;
    size_t off = 0;
    auto alloc = [&](size_t bytes) {
        void* p = ws + off;
        off = (off + bytes + 255) & ~(size_t)255;
        return p;
    };
    int*      rowptr = (int*)alloc((NN + 1) * sizeof(int));
    int*      cursor = (int*)alloc((NN + 1) * sizeof(int));
    int*      counts = (int*)alloc((size_t)NN * sizeof(int));
    int*      bsums  = (int*)alloc(64 * sizeof(int));
    int*      bex    = (int*)alloc(64 * sizeof(int));
    int*      csr    = (int*)alloc((size_t)TE * sizeof(int));
    float*    al     = (float*)alloc((size_t)NN * 4 * sizeof(float));
    _Float16* xs     = (_Float16*)alloc((size_t)NN * 128 * sizeof(_Float16));
    float*    h      = (float*)alloc((size_t)NN * 128 * sizeof(float));
    (void)ws_size; (void)n_in; (void)in_sizes; (void)out_size;

    const int NB = (NN + 1023) / 1024;       // 49
    const int GEMM_GRID = (NN + 63) / 64;    // 782
    const int AGG_GRID  = (NN + 3) / 4;      // 12500
    const int EDGE_GRID = 8 * ((TE + 255) / 256);   // 8x range-split

    (void)hipMemsetAsync(counts, 0, (size_t)NN * sizeof(int), stream);
    k_count<<<EDGE_GRID, 256, 0, stream>>>(ei, counts);
    k_bsum<<<NB, 1024, 0, stream>>>(counts, bsums);
    k_bscan<<<1, 64, 0, stream>>>(bsums, bex, NB);
    k_scan<<<NB, 1024, 0, stream>>>(counts, bex, rowptr, cursor);
    k_scatter<<<EDGE_GRID, 256, 0, stream>>>(ei, cursor, csr);

    k_gemm<<<GEMM_GRID, 256, 0, stream>>>(x, W1, as1, ad1, xs, al);
    k_agg<0><<<AGG_GRID, 256, 0, stream>>>(xs, al, rowptr, csr, b1, nullptr, nullptr, pa, h);
    k_gemm<<<GEMM_GRID, 256, 0, stream>>>(h, W2, as2, ad2, xs, al);
    k_agg<0><<<AGG_GRID, 256, 0, stream>>>(xs, al, rowptr, csr, b2, nullptr, nullptr, pa, h);
    k_gemm<<<GEMM_GRID, 256, 0, stream>>>(h, W3, as3, ad3, xs, al);
    k_agg<1><<<AGG_GRID, 256, 0, stream>>>(xs, al, rowptr, csr, b3, lpw, lpb, pa, out);
}

// Round 23
// 306.599 us; speedup vs baseline: 1.4937x; 1.0067x over previous
//
#include <hip/hip_runtime.h>

#define NN 50000
#define NE 800000
#define TE (NE + NN)
#define NRANGE 8
#define RSPAN ((NN + NRANGE - 1) / NRANGE)   // 6250

__device__ __forceinline__ float lrelu02(float x) { return x >= 0.f ? x : 0.2f * x; }

typedef const __attribute__((address_space(1))) unsigned int* gas_ptr;
typedef __attribute__((address_space(3))) unsigned int* las_ptr;
typedef _Float16 vh4 __attribute__((ext_vector_type(4)));
typedef _Float16 vh2 __attribute__((ext_vector_type(2)));
typedef unsigned int vu2 __attribute__((ext_vector_type(2)));
typedef float vf2 __attribute__((ext_vector_type(2)));

__device__ __forceinline__ void dma16g(const void* g, void* l) {
    __builtin_amdgcn_global_load_lds((gas_ptr)g, (las_ptr)l, 16, 0, 0);
}

// Count: 8x blocks; block (chunk, r=blockIdx&7) handles only dst-range r ->
// counts lines for range r are touched by one XCD only (round-robin dispatch).
__global__ void k_count(const int* __restrict__ ei, int* __restrict__ counts) {
    int r = blockIdx.x & 7;
    int e = (blockIdx.x >> 3) * 256 + threadIdx.x;
    if (e >= TE) return;
    int dst = (e < NE) ? ei[NE + e] : (e - NE);
    if (dst >= r * RSPAN && dst < (r + 1) * RSPAN)
        atomicAdd(&counts[dst], 1);
}

__global__ void k_bsum(const int* __restrict__ counts, int* __restrict__ bsums) {
    __shared__ int sm[1024];
    int i = blockIdx.x * 1024 + threadIdx.x;
    sm[threadIdx.x] = (i < NN) ? counts[i] : 0;
    __syncthreads();
    for (int off = 512; off > 0; off >>= 1) {
        if ((int)threadIdx.x < off) sm[threadIdx.x] += sm[threadIdx.x + off];
        __syncthreads();
    }
    if (threadIdx.x == 0) bsums[blockIdx.x] = sm[0];
}

__global__ void k_bscan(const int* __restrict__ bsums, int* __restrict__ bex, int nb) {
    int l = threadIdx.x;
    int v = (l < nb) ? bsums[l] : 0;
    int orig = v;
    for (int d = 1; d < 64; d <<= 1) {
        int t = __shfl_up(v, d);
        if (l >= d) v += t;
    }
    if (l <= nb) bex[l] = v - orig;
}

__global__ void k_scan(const int* __restrict__ counts, const int* __restrict__ bex,
                       int* __restrict__ rowptr, int* __restrict__ cursor) {
    __shared__ int sm[1024];
    int t = threadIdx.x;
    int i = blockIdx.x * 1024 + t;
    int c = (i < NN) ? counts[i] : 0;
    sm[t] = c;
    __syncthreads();
    for (int off = 1; off < 1024; off <<= 1) {
        int v = (t >= off) ? sm[t - off] : 0;
        __syncthreads();
        sm[t] += v;
        __syncthreads();
    }
    int ex = bex[blockIdx.x] + sm[t] - c;
    if (i <= NN) rowptr[i] = ex;
    if (i < NN) cursor[i] = ex;
}

// Scatter: 8x dst-range split -> csr lines of range r written from one XCD.
__global__ void k_scatter(const int* __restrict__ ei, int* __restrict__ cursor, int* __restrict__ csr) {
    int r = blockIdx.x & 7;
    int e = (blockIdx.x >> 3) * 256 + threadIdx.x;
    if (e >= TE) return;
    int dst = (e < NE) ? ei[NE + e] : (e - NE);
    if (dst >= r * RSPAN && dst < (r + 1) * RSPAN) {
        int src = (e < NE) ? ei[e] : dst;
        int pos = atomicAdd(&cursor[dst], 1);
        csr[pos] = src;
    }
}

// GEMM X[N,128] @ W[128,128] -> XS[N,128] (FP16) + AL logits (fp32).
// Templated input dtype: layer 1 reads fp32 x; layers 2/3 read fp16 h
// (halves the staged bytes + DMA count on the latency-critical path).
template <typename TIN>
__global__ __launch_bounds__(256) void k_gemm(const TIN* __restrict__ X, const float* __restrict__ W,
                                              const float* __restrict__ as_, const float* __restrict__ ad_,
                                              _Float16* __restrict__ XS, float* __restrict__ AL) {
    constexpr bool F16 = (sizeof(TIN) == 2);
    __shared__ TIN sX[64 * 128];   // 32 KB fp32 / 16 KB fp16
    int t = threadIdx.x;
    int lane = t & 63;
    int wv = __builtin_amdgcn_readfirstlane(t >> 6);
    int tc = t & 31;
    int tr = t >> 5;
    size_t chunk = (size_t)blockIdx.x * 64;
    size_t base = chunk * 128;
    if constexpr (F16) {
        const size_t gmax = (size_t)NN * 128 - 8;   // last valid 8-half chunk
#pragma unroll
        for (int i = 0; i < 4; i++) {
            size_t off = ((size_t)(i * 256 + t)) * 8;
            size_t g = base + off;
            if (g > gmax) g = gmax;
            dma16g(X + g, &sX[off]);
        }
    } else {
        const size_t gmax = (size_t)NN * 128 - 4;
#pragma unroll
        for (int i = 0; i < 8; i++) {
            size_t off = ((size_t)(wv * 8 + i)) * 256 + (size_t)lane * 4;
            size_t g = base + off;
            if (g > gmax) g = gmax;
            dma16g(X + g, &sX[off]);
        }
    }
    __syncthreads();
    float4 av = *(const float4*)(as_ + tc * 4);
    float4 dv = *(const float4*)(ad_ + tc * 4);
    float acc[8][4];
#pragma unroll
    for (int i = 0; i < 8; i++)
#pragma unroll
        for (int j = 0; j < 4; j++) acc[i][j] = 0.f;
#pragma unroll 2
    for (int kk = 0; kk < 128; kk += 4) {
        float4 wq[4];
#pragma unroll
        for (int k = 0; k < 4; k++)
            wq[k] = *(const float4*)(W + (size_t)(kk + k) * 128 + tc * 4);
#pragma unroll
        for (int i = 0; i < 8; i++) {
            float4 xv;
            if constexpr (F16) {
                vh4 hv = *(const vh4*)(&sX[(tr * 8 + i) * 128 + kk]);  // 8B half-wave broadcast
                xv.x = (float)hv.x; xv.y = (float)hv.y; xv.z = (float)hv.z; xv.w = (float)hv.w;
            } else {
                xv = *(const float4*)(&sX[(tr * 8 + i) * 128 + kk]);
            }
            acc[i][0] = fmaf(xv.x, wq[0].x, acc[i][0]);
            acc[i][1] = fmaf(xv.x, wq[0].y, acc[i][1]);
            acc[i][2] = fmaf(xv.x, wq[0].z, acc[i][2]);
            acc[i][3] = fmaf(xv.x, wq[0].w, acc[i][3]);
            acc[i][0] = fmaf(xv.y, wq[1].x, acc[i][0]);
            acc[i][1] = fmaf(xv.y, wq[1].y, acc[i][1]);
            acc[i][2] = fmaf(xv.y, wq[1].z, acc[i][2]);
            acc[i][3] = fmaf(xv.y, wq[1].w, acc[i][3]);
            acc[i][0] = fmaf(xv.z, wq[2].x, acc[i][0]);
            acc[i][1] = fmaf(xv.z, wq[2].y, acc[i][1]);
            acc[i][2] = fmaf(xv.z, wq[2].z, acc[i][2]);
            acc[i][3] = fmaf(xv.z, wq[2].w, acc[i][3]);
            acc[i][0] = fmaf(xv.w, wq[3].x, acc[i][0]);
            acc[i][1] = fmaf(xv.w, wq[3].y, acc[i][1]);
            acc[i][2] = fmaf(xv.w, wq[3].z, acc[i][2]);
            acc[i][3] = fmaf(xv.w, wq[3].w, acc[i][3]);
        }
    }
#pragma unroll
    for (int i = 0; i < 8; i++) {
        size_t row = chunk + tr * 8 + i;
        bool ok = row < NN;
        if (ok) {
            vh4 hv;
            hv.x = (_Float16)acc[i][0];
            hv.y = (_Float16)acc[i][1];
            hv.z = (_Float16)acc[i][2];
            hv.w = (_Float16)acc[i][3];
            vu2 u = __builtin_bit_cast(vu2, hv);
            __builtin_nontemporal_store(u, (vu2*)(XS + row * 128 + tc * 4));
        }
        float s = acc[i][0] * av.x + acc[i][1] * av.y + acc[i][2] * av.z + acc[i][3] * av.w;
        float dd = acc[i][0] * dv.x + acc[i][1] * dv.y + acc[i][2] * dv.z + acc[i][3] * dv.w;
#pragma unroll
        for (int off = 8; off > 0; off >>= 1) {
            s += __shfl_xor(s, off);
            dd += __shfl_xor(dd, off);
        }
        if (ok && (tc & 15) == 0) {
            int h = tc >> 4;
            AL[row * 4 + h] = s;
            AL[row * 4 + 2 + h] = dd;
        }
    }
}

// Aggregation: round-20 structure (proven 48us). FP16 gather operand, fp32
// accumulation. LAST=0 writes h as FP16 (NT u32); LAST=1 writes fp32 out[N].
template <int LAST>
__global__ __launch_bounds__(256) void k_agg(const _Float16* __restrict__ XS, const float* __restrict__ AL,
                                             const int* __restrict__ rowptr, const int* __restrict__ csr,
                                             const float* __restrict__ bias, const float* __restrict__ lp_w,
                                             const float* __restrict__ lp_b, const float* __restrict__ prelu_a,
                                             void* __restrict__ out_v) {
    int wv = threadIdx.x >> 6, lane = threadIdx.x & 63;
    int n = blockIdx.x * 4 + wv;
    if (n >= NN) return;
    int beg = rowptr[n], end = rowptr[n + 1];
    float2 aldv = *(const float2*)(AL + (size_t)n * 4 + 2);
    float ald0 = aldv.x, ald1 = aldv.y;
    float acc_lo = 0.f, acc_hi = 0.f, den0 = 0.f, den1 = 0.f;
    for (int base = beg; base < end; base += 64) {
        int i = base + lane;
        float w0 = 0.f, w1 = 0.f;
        int sv = 0;
        if (i < end) {
            sv = csr[i];
            float2 av = *(const float2*)(AL + (size_t)sv * 4);
            w0 = __expf(lrelu02(av.x + ald0));
            w1 = __expf(lrelu02(av.y + ald1));
        }
        den0 += w0;
        den1 += w1;
        int cnt = min(64, end - base);
        int j = 0;
        for (; j + 8 <= cnt; j += 8) {
            int s[8];
            float ww[8];
#pragma unroll
            for (int jj = 0; jj < 8; jj++) {
                s[jj] = __shfl(sv, j + jj);
                float q0 = __shfl(w0, j + jj), q1 = __shfl(w1, j + jj);
                ww[jj] = (lane < 32) ? q0 : q1;
            }
            vh2 xv[8];
#pragma unroll
            for (int jj = 0; jj < 8; jj++)
                xv[jj] = *(const vh2*)(XS + (size_t)s[jj] * 128 + 2 * lane);
#pragma unroll
            for (int jj = 0; jj < 8; jj++) {
                acc_lo = fmaf(ww[jj], (float)xv[jj].x, acc_lo);
                acc_hi = fmaf(ww[jj], (float)xv[jj].y, acc_hi);
            }
        }
        for (; j < cnt; j++) {
            int s = __shfl(sv, j);
            float q0 = __shfl(w0, j), q1 = __shfl(w1, j);
            float w = (lane < 32) ? q0 : q1;
            vh2 xv = *(const vh2*)(XS + (size_t)s * 128 + 2 * lane);
            acc_lo = fmaf(w, (float)xv.x, acc_lo);
            acc_hi = fmaf(w, (float)xv.y, acc_hi);
        }
    }
#pragma unroll
    for (int off = 32; off > 0; off >>= 1) {
        den0 += __shfl_xor(den0, off);
        den1 += __shfl_xor(den1, off);
    }
    float pa = prelu_a[0];
    float densel = (lane < 32) ? den0 : den1;
    float inv = 1.f / (densel + 1e-16f);
    if (LAST) {
        float* out = (float*)out_v;
        float hlo = acc_lo * inv, hhi = acc_hi * inv;
        float olo = __shfl_xor(hlo, 32), ohi = __shfl_xor(hhi, 32);
        float p = 0.f;
        if (lane < 32) {
            int c = 2 * lane;
            float v0 = 0.5f * (hlo + olo) + bias[c];
            float v1 = 0.5f * (hhi + ohi) + bias[c + 1];
            v0 = v0 >= 0.f ? v0 : pa * v0;
            v1 = v1 >= 0.f ? v1 : pa * v1;
            p = v0 * lp_w[c] + v1 * lp_w[c + 1];
        }
#pragma unroll
        for (int off = 32; off > 0; off >>= 1) p += __shfl_xor(p, off);
        if (lane == 0) out[n] = p + lp_b[0];
    } else {
        _Float16* out = (_Float16*)out_v;
        int c = 2 * lane;
        float2 bv = *(const float2*)(bias + c);
        float v0 = acc_lo * inv + bv.x;
        float v1 = acc_hi * inv + bv.y;
        v0 = v0 >= 0.f ? v0 : pa * v0;
        v1 = v1 >= 0.f ? v1 : pa * v1;
        vh2 hv; hv.x = (_Float16)v0; hv.y = (_Float16)v1;
        unsigned int u = __builtin_bit_cast(unsigned int, hv);
        __builtin_nontemporal_store(u, (unsigned int*)(out + (size_t)n * 128 + c));
    }
}

extern "C" void kernel_launch(void* const* d_in, const int* in_sizes, int n_in,
                              void* d_out, int out_size, void* d_ws, size_t ws_size,
                              hipStream_t stream) {
    const float* x   = (const float*)d_in[0];
    const int*   ei  = (const int*)d_in[1];
    const float* W1  = (const float*)d_in[2];
    const float* as1 = (const float*)d_in[3];
    const float* ad1 = (const float*)d_in[4];
    const float* b1  = (const float*)d_in[5];
    const float* W2  = (const float*)d_in[6];
    const float* as2 = (const float*)d_in[7];
    const float* ad2 = (const float*)d_in[8];
    const float* b2  = (const float*)d_in[9];
    const float* W3  = (const float*)d_in[10];
    const float* as3 = (const float*)d_in[11];
    const float* ad3 = (const float*)d_in[12];
    const float* b3  = (const float*)d_in[13];
    const float* lpw = (const float*)d_in[14];
    const float* lpb = (const float*)d_in[15];
    const float* pa  = (const float*)d_in[16];
    float* out = (float*)d_out;

    char* ws = (char*)d_ws;
    size_t off = 0;
    auto alloc = [&](size_t bytes) {
        void* p = ws + off;
        off = (off + bytes + 255) & ~(size_t)255;
        return p;
    };
    int*      rowptr = (int*)alloc((NN + 1) * sizeof(int));
    int*      cursor = (int*)alloc((NN + 1) * sizeof(int));
    int*      counts = (int*)alloc((size_t)NN * sizeof(int));
    int*      bsums  = (int*)alloc(64 * sizeof(int));
    int*      bex    = (int*)alloc(64 * sizeof(int));
    int*      csr    = (int*)alloc((size_t)TE * sizeof(int));
    float*    al     = (float*)alloc((size_t)NN * 4 * sizeof(float));
    _Float16* xs     = (_Float16*)alloc((size_t)NN * 128 * sizeof(_Float16));
    _Float16* h      = (_Float16*)alloc((size_t)NN * 128 * sizeof(_Float16));
    (void)ws_size; (void)n_in; (void)in_sizes; (void)out_size;

    const int NB = (NN + 1023) / 1024;       // 49
    const int GEMM_GRID = (NN + 63) / 64;    // 782
    const int AGG_GRID  = (NN + 3) / 4;      // 12500
    const int EDGE_GRID = 8 * ((TE + 255) / 256);   // 8x range-split

    (void)hipMemsetAsync(counts, 0, (size_t)NN * sizeof(int), stream);
    k_count<<<EDGE_GRID, 256, 0, stream>>>(ei, counts);
    k_bsum<<<NB, 1024, 0, stream>>>(counts, bsums);
    k_bscan<<<1, 64, 0, stream>>>(bsums, bex, NB);
    k_scan<<<NB, 1024, 0, stream>>>(counts, bex, rowptr, cursor);
    k_scatter<<<EDGE_GRID, 256, 0, stream>>>(ei, cursor, csr);

    k_gemm<float><<<GEMM_GRID, 256, 0, stream>>>(x, W1, as1, ad1, xs, al);
    k_agg<0><<<AGG_GRID, 256, 0, stream>>>(xs, al, rowptr, csr, b1, nullptr, nullptr, pa, h);
    k_gemm<_Float16><<<GEMM_GRID, 256, 0, stream>>>(h, W2, as2, ad2, xs, al);
    k_agg<0><<<AGG_GRID, 256, 0, stream>>>(xs, al, rowptr, csr, b2, nullptr, nullptr, pa, h);
    k_gemm<_Float16><<<GEMM_GRID, 256, 0, stream>>>(h, W3, as3, ad3, xs, al);
    k_agg<1><<<AGG_GRID, 256, 0, stream>>>(xs, al, rowptr, csr, b3, lpw, lpb, pa, out);
}